// Round 10
// baseline (292.675 us; speedup 1.0000x reference)
//
#include <hip/hip_runtime.h>
#include <math.h>

#define NPTS   65536
#define DIM    128
#define KCODES 4096

constexpr float DECAY_F         = 0.99f;
constexpr float ONE_MINUS_DECAY = 0.01f;
constexpr float EPS_F           = 1e-5f;

// d_out layout (floats): quantize_st[N*D] | embed_ind[N] | loss[1] | new_embed[K*D] | new_cluster_size[K]
constexpr int OFF_IDX  = NPTS * DIM;
constexpr int OFF_LOSS = OFF_IDX + NPTS;
constexpr int OFF_EMB  = OFF_LOSS + 1;
constexpr int OFF_NCS  = OFF_EMB + KCODES * DIM;

typedef _Float16 half8 __attribute__((ext_vector_type(8)));
typedef _Float16 half4 __attribute__((ext_vector_type(4)));
typedef float    f32x4 __attribute__((ext_vector_type(4)));

// ---------------- prep: E image + esq + ALL buffer init (no memsets) ----------------
__global__ __launch_bounds__(256) void vq_prep_kernel(const float* __restrict__ embed,
                                                      float* __restrict__ esq,
                                                      unsigned char* __restrict__ Eimg,
                                                      unsigned long long* __restrict__ rowpack,
                                                      unsigned int* __restrict__ counts,
                                                      float* __restrict__ esum,
                                                      float* __restrict__ out) {
    __shared__ float sq[512];
    int b = blockIdx.x, t = threadIdx.x;

    rowpack[b * 512 + t]       = ~0ULL;
    rowpack[b * 512 + 256 + t] = ~0ULL;
    if (t < 32) counts[b * 32 + t] = 0u;
    if (b == 0 && t == 0) out[OFF_LOSS] = 0.f;

    {
        float4* ez = (float4*)esum;
#pragma unroll
        for (int j = 0; j < 4; ++j) ez[(size_t)b * 1024 + j * 256 + t] = (float4){0.f, 0.f, 0.f, 0.f};
    }

    unsigned char* img = Eimg + ((size_t)b << 14);
#pragma unroll
    for (int it = 0; it < 2; ++it) {
        int idx = t + it * 256;            // 0..511 : (r 0..31, c8 0..15)
        int r = idx >> 4, c8 = idx & 15;
        const float4* src = (const float4*)(embed + (size_t)(b * 32 + r) * DIM + c8 * 8);
        float4 v0 = src[0], v1 = src[1];
        float e[8] = {v0.x, v0.y, v0.z, v0.w, v1.x, v1.y, v1.z, v1.w};
        half8 h8, l8;
        float ss = 0.f;
#pragma unroll
        for (int j = 0; j < 8; ++j) {
            _Float16 h = (_Float16)e[j];
            h8[j] = h;
            l8[j] = (_Float16)(e[j] - (float)h);
            ss = fmaf(e[j], e[j], ss);
        }
        int bo = r * 256 + ((c8 * 16) ^ ((r & 7) << 4));
        *(half8*)(img + bo)        = h8;
        *(half8*)(img + 8192 + bo) = l8;
        sq[idx] = ss;
    }
    __syncthreads();
    if (t < 32) {
        float s = 0.f;
#pragma unroll
        for (int c = 0; c < 16; ++c) s += sq[t * 16 + c];
        esq[b * 32 + t] = s;
    }
}

// ---------------- main: K-split MFMA argmin; deferred min-update (2 acc banks) ----------------
__global__ __launch_bounds__(256, 4)
void vq_main_kernel(const float* __restrict__ x, const float* __restrict__ esq,
                    const unsigned char* __restrict__ Eimg,
                    unsigned long long* __restrict__ rowpack,
                    unsigned int* __restrict__ counts,
                    int* __restrict__ sidx,
                    float* __restrict__ out) {
    __shared__ __align__(16) unsigned char lds[40960];   // 32KB E dbuf + 8KB esq

    const int tid  = threadIdx.x;
    const int l    = tid & 63;
    const int w    = tid >> 6;          // 0..3
    const int mblk = blockIdx.x >> 1;
    const int half = blockIdx.x & 1;
    const int row0 = mblk * 128;

    // esq for this half -> LDS
    {
        const float4* eq = (const float4*)(esq + half * 2048);
        float4* dst = (float4*)(lds + 32768);
        dst[tid]       = eq[tid];
        dst[tid + 256] = eq[tid + 256];
    }

    // ---- X prologue: two 64-row phases through LDS; A = -2x f16 hi/lo -> registers ----
    half8 ahi[2][4], alo[2][4];
#pragma unroll
    for (int ph = 0; ph < 2; ++ph) {
        if (ph) __syncthreads();
        const float4* xg = (const float4*)(x + (size_t)(row0 + ph * 64) * DIM);
#pragma unroll
        for (int it = 0; it < 8; ++it) {
            int i4 = tid + it * 256;           // 0..2047 : 64 rows x 32 f4
            int r = i4 >> 5, c4 = i4 & 31;
            float4 v = xg[i4];
            float m0 = -2.f * v.x, m1 = -2.f * v.y, m2 = -2.f * v.z, m3 = -2.f * v.w;
            half4 h, lo;
            h[0] = (_Float16)m0; h[1] = (_Float16)m1; h[2] = (_Float16)m2; h[3] = (_Float16)m3;
            lo[0] = (_Float16)(m0 - (float)h[0]); lo[1] = (_Float16)(m1 - (float)h[1]);
            lo[2] = (_Float16)(m2 - (float)h[2]); lo[3] = (_Float16)(m3 - (float)h[3]);
            int bo = r * 256 + ((c4 * 8) ^ ((r & 7) << 4));
            *(half4*)(lds + bo)         = h;
            *(half4*)(lds + 16384 + bo) = lo;
        }
        __syncthreads();
        if ((w >> 1) == ph) {
#pragma unroll
            for (int rf = 0; rf < 2; ++rf)
#pragma unroll
                for (int ks = 0; ks < 4; ++ks) {
                    int rloc = (w & 1) * 32 + rf * 16 + (l & 15);
                    int bo = rloc * 256 + ((ks * 64 + (l >> 4) * 16) ^ ((rloc & 7) << 4));
                    ahi[rf][ks] = *(const half8*)(lds + bo);
                    alo[rf][ks] = *(const half8*)(lds + 16384 + bo);
                }
        }
    }
    __syncthreads();   // lds[0..32768] becomes E double-buffer (16KB each)

#define STAGE(P, CT)                                                                     \
    {                                                                                    \
        const unsigned char* gsrc = Eimg + ((size_t)(half * 64 + (CT)) << 14);           \
        _Pragma("unroll")                                                                \
        for (int t = 0; t < 4; ++t) {                                                    \
            __builtin_amdgcn_global_load_lds(                                            \
                (const __attribute__((address_space(1))) unsigned int*)(gsrc + t * 4096 + w * 1024 + l * 16), \
                (__attribute__((address_space(3))) unsigned int*)(lds + (P) * 16384 + t * 4096 + w * 1024),   \
                16, 0, 0);                                                               \
        }                                                                                \
    }

// MFMA phase for iteration CT into bank ACC (tile P). Ends after setprio(0);
// caller appends deferred min-update of the OTHER bank, then the tile-protect barrier.
#define MFMA_PHASE(ACC, P, CT)                                                           \
    {                                                                                    \
        if ((CT) < 63) {                                                                 \
            STAGE((P) ^ 1, (CT) + 1);                                                    \
            asm volatile("s_waitcnt vmcnt(4)" ::: "memory");                             \
        } else {                                                                         \
            asm volatile("s_waitcnt vmcnt(0)" ::: "memory");                             \
        }                                                                                \
        __builtin_amdgcn_s_barrier();                                                    \
        const unsigned char* bb = lds + (P) * 16384;                                     \
        {                                                                                \
            float e0 = esql[(CT) * 32 + (l & 15)];                                       \
            float e1 = esql[(CT) * 32 + 16 + (l & 15)];                                  \
            ACC[0][0] = (f32x4){e0, e0, e0, e0};                                         \
            ACC[1][0] = (f32x4){e0, e0, e0, e0};                                         \
            ACC[0][1] = (f32x4){e1, e1, e1, e1};                                         \
            ACC[1][1] = (f32x4){e1, e1, e1, e1};                                         \
        }                                                                                \
        __builtin_amdgcn_s_setprio(1);                                                   \
        _Pragma("unroll")                                                                \
        for (int ks = 0; ks < 4; ++ks) {                                                 \
            _Pragma("unroll")                                                            \
            for (int cf = 0; cf < 2; ++cf) {                                             \
                int rowb = cf * 16 + (l & 15);                                           \
                int bo = rowb * 256 + ((ks * 64 + (l >> 4) * 16) ^ ((rowb & 7) << 4));   \
                half8 bh = *(const half8*)(bb + bo);                                     \
                half8 bl = *(const half8*)(bb + 8192 + bo);                              \
                ACC[0][cf] = __builtin_amdgcn_mfma_f32_16x16x32_f16(ahi[0][ks], bh, ACC[0][cf], 0, 0, 0); \
                ACC[1][cf] = __builtin_amdgcn_mfma_f32_16x16x32_f16(ahi[1][ks], bh, ACC[1][cf], 0, 0, 0); \
                ACC[0][cf] = __builtin_amdgcn_mfma_f32_16x16x32_f16(alo[0][ks], bh, ACC[0][cf], 0, 0, 0); \
                ACC[1][cf] = __builtin_amdgcn_mfma_f32_16x16x32_f16(alo[1][ks], bh, ACC[1][cf], 0, 0, 0); \
                ACC[0][cf] = __builtin_amdgcn_mfma_f32_16x16x32_f16(ahi[0][ks], bl, ACC[0][cf], 0, 0, 0); \
                ACC[1][cf] = __builtin_amdgcn_mfma_f32_16x16x32_f16(ahi[1][ks], bl, ACC[1][cf], 0, 0, 0); \
            }                                                                            \
        }                                                                                \
        __builtin_amdgcn_s_setprio(0);                                                   \
    }

#define MIN_UPDATE(ACC, CT)                                                              \
    {                                                                                    \
        _Pragma("unroll")                                                                \
        for (int rf = 0; rf < 2; ++rf)                                                   \
            _Pragma("unroll")                                                            \
            for (int cf = 0; cf < 2; ++cf) {                                             \
                int kidx = half * 2048 + (CT) * 32 + cf * 16 + (l & 15);                 \
                _Pragma("unroll")                                                        \
                for (int r = 0; r < 4; ++r) {                                            \
                    float v = ACC[rf][cf][r];                                            \
                    if (v < minv[rf][r]) { minv[rf][r] = v; mini[rf][r] = kidx; }        \
                }                                                                        \
            }                                                                            \
    }

    float minv[2][4];
    int   mini[2][4];
#pragma unroll
    for (int rf = 0; rf < 2; ++rf)
#pragma unroll
        for (int r = 0; r < 4; ++r) { minv[rf][r] = 3.4e38f; mini[rf][r] = 0; }

    const float* esql = (const float*)(lds + 32768);
    f32x4 accA[2][2], accB[2][2];

    STAGE(0, 0);

    // ct = 0 (bank A, tile 0), no deferred update yet
    MFMA_PHASE(accA, 0, 0);
    __builtin_amdgcn_s_barrier();

    for (int ct2 = 0; ct2 < 31; ++ct2) {
        const int ctO = 2 * ct2 + 1;
        MFMA_PHASE(accB, 1, ctO);        // compute ct (odd) into B
        MIN_UPDATE(accA, ctO - 1);       // deferred update of ct-1 (bank A) in MFMA shadow
        __builtin_amdgcn_s_barrier();
        MFMA_PHASE(accA, 0, ctO + 1);    // compute ct+1 (even) into A
        MIN_UPDATE(accB, ctO);           // deferred update of ct (bank B)
        __builtin_amdgcn_s_barrier();
    }
    MFMA_PHASE(accB, 1, 63);
    MIN_UPDATE(accA, 62);
    MIN_UPDATE(accB, 63);

    // argmin reduce across the 16 col-lanes (low 4 lane bits)
#pragma unroll
    for (int off = 1; off < 16; off <<= 1) {
#pragma unroll
        for (int rf = 0; rf < 2; ++rf)
#pragma unroll
            for (int r = 0; r < 4; ++r) {
                float v2 = __shfl_xor(minv[rf][r], off);
                int   i2 = __shfl_xor(mini[rf][r], off);
                if (v2 < minv[rf][r] || (v2 == minv[rf][r] && i2 < mini[rf][r])) {
                    minv[rf][r] = v2; mini[rf][r] = i2;
                }
            }
    }
    if ((l & 15) == 0) {
#pragma unroll
        for (int rf = 0; rf < 2; ++rf)
#pragma unroll
            for (int r = 0; r < 4; ++r) {
                int row = row0 + w * 32 + rf * 16 + (l >> 4) * 4 + r;   // C/D: row=(l>>4)*4+reg
                unsigned int u = __float_as_uint(minv[rf][r]);
                u = (u & 0x80000000u) ? ~u : (u | 0x80000000u);
                unsigned long long key = ((unsigned long long)u << 32) | (unsigned int)mini[rf][r];
                unsigned long long old = atomicMin(&rowpack[row], key);
                if (old != ~0ULL) {
                    unsigned long long fin = old < key ? old : key;
                    int kf = (int)(fin & 0xFFFFFFFFu);
                    out[OFF_IDX + row] = (float)kf;
                    sidx[row] = kf;
                    atomicAdd(&counts[kf], 1u);
                }
            }
    }
}

// ---------------- scan: shfl-based prefix sum of counts; ncs, inv_sm ----------------
__global__ __launch_bounds__(256) void vq_scan_kernel(const unsigned int* __restrict__ counts,
                                                      const float* __restrict__ cs,
                                                      float* __restrict__ out,
                                                      int* __restrict__ offsets,
                                                      int* __restrict__ cursor,
                                                      float* __restrict__ inv_sm) {
    __shared__ int   wsum[4];
    __shared__ float wnsum[4];
    int tid = threadIdx.x, l = tid & 63, w = tid >> 6;

    unsigned int c[16];
    float vl[16];
    int   csum = 0;
    float nsum = 0.f;
#pragma unroll
    for (int j = 0; j < 16; ++j) {
        int i = tid * 16 + j;
        c[j] = counts[i];
        csum += (int)c[j];
        float v = fmaf(cs[i], DECAY_F, (float)c[j] * ONE_MINUS_DECAY);
        vl[j] = v;
        nsum += v;
        out[OFF_NCS + i] = v;
    }

    int inc = csum;
#pragma unroll
    for (int off = 1; off < 64; off <<= 1) {
        int t = __shfl_up(inc, off);
        if (l >= off) inc += t;
    }
    float nred = nsum;
#pragma unroll
    for (int off = 32; off >= 1; off >>= 1) nred += __shfl_xor(nred, off);

    if (l == 63) wsum[w] = inc;
    if (l == 0)  wnsum[w] = nred;
    __syncthreads();

    int wpre = 0;
    for (int i = 0; i < w; ++i) wpre += wsum[i];
    float ntot = wnsum[0] + wnsum[1] + wnsum[2] + wnsum[3];
    float num  = ntot + (float)KCODES * EPS_F;

    int off_ = wpre + inc - csum;
#pragma unroll
    for (int j = 0; j < 16; ++j) {
        int i = tid * 16 + j;
        offsets[i] = off_;
        cursor[i]  = off_;
        off_ += (int)c[j];
        inv_sm[i] = num / ((vl[j] + EPS_F) * ntot);
    }
}

// ---------------- sort: bucket rows by code; emit rowids + skey ----------------
__global__ __launch_bounds__(256) void vq_sort_kernel(const int* __restrict__ sidx,
                                                      int* __restrict__ cursor,
                                                      int* __restrict__ rowids,
                                                      int* __restrict__ skey) {
    int r = blockIdx.x * 256 + threadIdx.x;
    int k = sidx[r];
    int pos = atomicAdd(&cursor[k], 1);
    rowids[pos] = r;
    skey[pos]   = k;
}

// ---------------- segsum: position-parallel sorted segment sum (run-flush) ----------------
__global__ __launch_bounds__(256) void vq_segsum_kernel(const float* __restrict__ x,
                                                        const float* __restrict__ embed,
                                                        const int* __restrict__ rowids,
                                                        const int* __restrict__ skey,
                                                        const int* __restrict__ offsets,
                                                        const unsigned int* __restrict__ counts,
                                                        float* __restrict__ esum,
                                                        float* __restrict__ out) {
    __shared__ float buck[64][DIM];     // 32 KB
    __shared__ int   rid_s[64], rank_s[64], bcode_s[64];
    __shared__ int   nseg_s;
    __shared__ float lred[4];

    const int tid = threadIdx.x;
    const int w   = tid >> 6, l = tid & 63;
    const int p0  = blockIdx.x * 64;

    {
        float4* bz = (float4*)&buck[0][0];
#pragma unroll
        for (int j = 0; j < 8; ++j) bz[j * 256 + tid] = (float4){0.f, 0.f, 0.f, 0.f};
    }

    if (tid < 64) {
        int p = p0 + tid;
        int k = skey[p];
        rid_s[tid] = rowids[p];
        int f = (tid == 0) ? 1 : (k != skey[p - 1] ? 1 : 0);
        int inc = f;
#pragma unroll
        for (int off = 1; off < 64; off <<= 1) {
            int t = __shfl_up(inc, off);
            if (tid >= off) inc += t;
        }
        int rank = inc - 1;
        rank_s[tid] = rank;
        if (f) bcode_s[rank] = k;
        if (tid == 63) nseg_s = inc;
    }
    __syncthreads();

    float lsum = 0.f;
    {
        int prevb = rank_s[w * 16];
        float2 ev = *(const float2*)(embed + (size_t)bcode_s[prevb] * DIM + l * 2);
        float ra0 = 0.f, ra1 = 0.f;
#pragma unroll 4
        for (int i = 0; i < 16; ++i) {
            int pl = w * 16 + i;
            int r  = rid_s[pl];
            int b  = rank_s[pl];
            if (b != prevb) {
                atomicAdd(&buck[prevb][l * 2],     ra0);
                atomicAdd(&buck[prevb][l * 2 + 1], ra1);
                ra0 = 0.f; ra1 = 0.f;
                prevb = b;
                ev = *(const float2*)(embed + (size_t)bcode_s[b] * DIM + l * 2);
            }
            float2 xv = *(const float2*)(x + (size_t)r * DIM + l * 2);
            *(float2*)(out + (size_t)r * DIM + l * 2) = ev;     // quantize gather
            ra0 += xv.x; ra1 += xv.y;
            float d0 = ev.x - xv.x, d1 = ev.y - xv.y;
            lsum = fmaf(d0, d0, fmaf(d1, d1, lsum));
        }
        atomicAdd(&buck[prevb][l * 2],     ra0);
        atomicAdd(&buck[prevb][l * 2 + 1], ra1);
    }

#pragma unroll
    for (int s = 32; s >= 1; s >>= 1) lsum += __shfl_xor(lsum, s);
    if (l == 0) lred[w] = lsum;
    __syncthreads();

    int nseg = nseg_s;
    for (int b = w; b < nseg; b += 4) {
        int kb = bcode_s[b];
        int o  = offsets[kb];
        int c  = (int)counts[kb];
        float v0 = buck[b][l * 2], v1 = buck[b][l * 2 + 1];
        if (o >= p0 && o + c <= p0 + 64) {
            *(float2*)(esum + (size_t)kb * DIM + l * 2) = (float2){v0, v1};
        } else {
            atomicAdd(esum + (size_t)kb * DIM + l * 2,     v0);
            atomicAdd(esum + (size_t)kb * DIM + l * 2 + 1, v1);
        }
    }

    if (tid == 0) {
        float bl = (lred[0] + lred[1]) + (lred[2] + lred[3]);
        atomicAdd(out + OFF_LOSS, bl * (1.0f / ((float)NPTS * (float)DIM)));
    }
}

// ---------------- embed: new_embed = (eavg*0.99 + esum*0.01) * inv_sm ----------------
__global__ __launch_bounds__(256) void vq_embed_kernel(const float* __restrict__ eavg,
                                                       const float* __restrict__ esum,
                                                       const float* __restrict__ inv_sm,
                                                       float* __restrict__ out) {
    int i = blockIdx.x * 256 + threadIdx.x;
    int k = i >> 7;
    out[OFF_EMB + i] = fmaf(eavg[i], DECAY_F, esum[i] * ONE_MINUS_DECAY) * inv_sm[k];
}

extern "C" void kernel_launch(void* const* d_in, const int* in_sizes, int n_in,
                              void* d_out, int out_size, void* d_ws, size_t ws_size,
                              hipStream_t stream) {
    const float* x     = (const float*)d_in[0];
    const float* embed = (const float*)d_in[1];
    const float* cs    = (const float*)d_in[2];
    const float* eavg  = (const float*)d_in[3];
    float* out = (float*)d_out;

    // ws: rowpack[N] u64 | esq[K] | inv_sm[K] | counts[K] | offsets[K] | cursor[K] |
    //     rowids[N] | sidx[N] | skey[N] | esum[K*D] | Eimg 2MB   (~5.9 MB)
    unsigned long long* rowpack = (unsigned long long*)d_ws;
    float*         esq     = (float*)(rowpack + NPTS);
    float*         inv_sm  = esq + KCODES;
    unsigned int*  counts  = (unsigned int*)(inv_sm + KCODES);
    int*           offsets = (int*)(counts + KCODES);
    int*           cursor  = offsets + KCODES;
    int*           rowids  = cursor + KCODES;
    int*           sidx    = rowids + NPTS;
    int*           skey    = sidx + NPTS;
    float*         esum    = (float*)(skey + NPTS);
    unsigned char* Eimg    = (unsigned char*)(esum + KCODES * DIM);

    vq_prep_kernel<<<KCODES / 32, 256, 0, stream>>>(embed, esq, Eimg, rowpack, counts, esum, out);
    vq_main_kernel<<<NPTS / 128 * 2, 256, 0, stream>>>(x, esq, Eimg, rowpack, counts, sidx, out);
    vq_scan_kernel<<<1, 256, 0, stream>>>(counts, cs, out, offsets, cursor, inv_sm);
    vq_sort_kernel<<<NPTS / 256, 256, 0, stream>>>(sidx, cursor, rowids, skey);
    vq_segsum_kernel<<<NPTS / 64, 256, 0, stream>>>(x, embed, rowids, skey, offsets, counts, esum, out);
    vq_embed_kernel<<<(KCODES * DIM) / 256, 256, 0, stream>>>(eavg, esum, inv_sm, out);
}

// Round 11
// 271.890 us; speedup vs baseline: 1.0764x; 1.0764x over previous
//
#include <hip/hip_runtime.h>
#include <math.h>

#define NPTS   65536
#define DIM    128
#define KCODES 4096

constexpr float DECAY_F         = 0.99f;
constexpr float ONE_MINUS_DECAY = 0.01f;
constexpr float EPS_F           = 1e-5f;

// d_out layout (floats): quantize_st[N*D] | embed_ind[N] | loss[1] | new_embed[K*D] | new_cluster_size[K]
constexpr int OFF_IDX  = NPTS * DIM;
constexpr int OFF_LOSS = OFF_IDX + NPTS;
constexpr int OFF_EMB  = OFF_LOSS + 1;
constexpr int OFF_NCS  = OFF_EMB + KCODES * DIM;

typedef _Float16 half8 __attribute__((ext_vector_type(8)));
typedef _Float16 half4 __attribute__((ext_vector_type(4)));
typedef float    f32x16 __attribute__((ext_vector_type(16)));

// ---------------- prep: E image + esq + ALL buffer init (no memsets) ----------------
__global__ __launch_bounds__(256) void vq_prep_kernel(const float* __restrict__ embed,
                                                      float* __restrict__ esq,
                                                      unsigned char* __restrict__ Eimg,
                                                      unsigned long long* __restrict__ rowpack,
                                                      unsigned int* __restrict__ counts,
                                                      float* __restrict__ esum,
                                                      float* __restrict__ out) {
    __shared__ float sq[512];
    int b = blockIdx.x, t = threadIdx.x;

    rowpack[b * 512 + t]       = ~0ULL;
    rowpack[b * 512 + 256 + t] = ~0ULL;
    if (t < 32) counts[b * 32 + t] = 0u;
    if (b == 0 && t == 0) out[OFF_LOSS] = 0.f;

    {
        float4* ez = (float4*)esum;
#pragma unroll
        for (int j = 0; j < 4; ++j) ez[(size_t)b * 1024 + j * 256 + t] = (float4){0.f, 0.f, 0.f, 0.f};
    }

    unsigned char* img = Eimg + ((size_t)b << 14);
#pragma unroll
    for (int it = 0; it < 2; ++it) {
        int idx = t + it * 256;            // 0..511 : (r 0..31, c8 0..15)
        int r = idx >> 4, c8 = idx & 15;
        const float4* src = (const float4*)(embed + (size_t)(b * 32 + r) * DIM + c8 * 8);
        float4 v0 = src[0], v1 = src[1];
        float e[8] = {v0.x, v0.y, v0.z, v0.w, v1.x, v1.y, v1.z, v1.w};
        half8 h8, l8;
        float ss = 0.f;
#pragma unroll
        for (int j = 0; j < 8; ++j) {
            _Float16 h = (_Float16)e[j];
            h8[j] = h;
            l8[j] = (_Float16)(e[j] - (float)h);
            ss = fmaf(e[j], e[j], ss);
        }
        int bo = r * 256 + ((c8 * 16) ^ ((r & 7) << 4));
        *(half8*)(img + bo)        = h8;
        *(half8*)(img + 8192 + bo) = l8;
        sq[idx] = ss;
    }
    __syncthreads();
    if (t < 32) {
        float s = 0.f;
#pragma unroll
        for (int c = 0; c < 16; ++c) s += sq[t * 16 + c];
        esq[b * 32 + t] = s;
    }
}

// ---------------- main: K-split argmin via mfma_f32_32x32x16_f16 (R9 skeleton) ----------------
// grid 1024: mblk = bid>>1 (128 rows), half = bid&1 (2048 codes). Wave owns 32 rows.
__global__ __launch_bounds__(256, 3)
void vq_main_kernel(const float* __restrict__ x, const float* __restrict__ esq,
                    const unsigned char* __restrict__ Eimg,
                    unsigned long long* __restrict__ rowpack,
                    unsigned int* __restrict__ counts,
                    int* __restrict__ sidx,
                    float* __restrict__ out) {
    __shared__ __align__(16) unsigned char lds[40960];   // 32KB E dbuf + 8KB esq

    const int tid  = threadIdx.x;
    const int l    = tid & 63;
    const int w    = tid >> 6;          // 0..3
    const int c31  = l & 31;
    const int h2   = l >> 5;
    const int mblk = blockIdx.x >> 1;
    const int half = blockIdx.x & 1;
    const int row0 = mblk * 128;

    // esq for this half -> LDS
    {
        const float4* eq = (const float4*)(esq + half * 2048);
        float4* dst = (float4*)(lds + 32768);
        dst[tid]       = eq[tid];
        dst[tid + 256] = eq[tid + 256];
    }

    // ---- X prologue: two 64-row phases through LDS; A = -2x f16 hi/lo -> registers ----
    // A frag (32x32x16): lane l -> row = c31, k = h2*8 + j  (same k-pattern as B, so
    // any hardware k-ordering cancels between operands).
    half8 ahi[8], alo[8];
#pragma unroll
    for (int ph = 0; ph < 2; ++ph) {
        if (ph) __syncthreads();
        const float4* xg = (const float4*)(x + (size_t)(row0 + ph * 64) * DIM);
#pragma unroll
        for (int it = 0; it < 8; ++it) {
            int i4 = tid + it * 256;           // 0..2047 : 64 rows x 32 f4
            int r = i4 >> 5, c4 = i4 & 31;
            float4 v = xg[i4];
            float m0 = -2.f * v.x, m1 = -2.f * v.y, m2 = -2.f * v.z, m3 = -2.f * v.w;
            half4 h, lo;
            h[0] = (_Float16)m0; h[1] = (_Float16)m1; h[2] = (_Float16)m2; h[3] = (_Float16)m3;
            lo[0] = (_Float16)(m0 - (float)h[0]); lo[1] = (_Float16)(m1 - (float)h[1]);
            lo[2] = (_Float16)(m2 - (float)h[2]); lo[3] = (_Float16)(m3 - (float)h[3]);
            int bo = r * 256 + ((c4 * 8) ^ ((r & 7) << 4));
            *(half4*)(lds + bo)         = h;
            *(half4*)(lds + 16384 + bo) = lo;
        }
        __syncthreads();
        if ((w >> 1) == ph) {
            int rloc = (w & 1) * 32 + c31;
#pragma unroll
            for (int ks = 0; ks < 8; ++ks) {
                int bo = rloc * 256 + ((ks * 32 + h2 * 16) ^ ((rloc & 7) << 4));
                ahi[ks] = *(const half8*)(lds + bo);
                alo[ks] = *(const half8*)(lds + 16384 + bo);
            }
        }
    }
    __syncthreads();   // lds[0..32768] becomes E double-buffer (16KB each)

#define STAGE(P, CT)                                                                     \
    {                                                                                    \
        const unsigned char* gsrc = Eimg + ((size_t)(half * 64 + (CT)) << 14);           \
        _Pragma("unroll")                                                                \
        for (int t = 0; t < 4; ++t) {                                                    \
            __builtin_amdgcn_global_load_lds(                                            \
                (const __attribute__((address_space(1))) unsigned int*)(gsrc + t * 4096 + w * 1024 + l * 16), \
                (__attribute__((address_space(3))) unsigned int*)(lds + (P) * 16384 + t * 4096 + w * 1024),   \
                16, 0, 0);                                                               \
        }                                                                                \
    }

    float minv[16];
    int   mini[16];
#pragma unroll
    for (int j = 0; j < 16; ++j) { minv[j] = 3.4e38f; mini[j] = 0; }

    const float* esql = (const float*)(lds + 32768);
    STAGE(0, 0);

    for (int ct = 0; ct < 64; ++ct) {
        const int p = ct & 1;
        if (ct < 63) {
            STAGE(p ^ 1, ct + 1);
            asm volatile("s_waitcnt vmcnt(4)" ::: "memory");
        } else {
            asm volatile("s_waitcnt vmcnt(0)" ::: "memory");
        }
        __builtin_amdgcn_s_barrier();   // all waves' tile-p loads landed

        const unsigned char* bb = lds + p * 16384;

        // esq folded into chain-1 init; chain-2 starts at 0 (summed at min-update)
        float e = esql[ct * 32 + c31];
        f32x16 acc1, acc2;
#pragma unroll
        for (int j = 0; j < 16; ++j) { acc1[j] = e; acc2[j] = 0.f; }

        __builtin_amdgcn_s_setprio(1);
#pragma unroll
        for (int ks = 0; ks < 8; ++ks) {
            int bo = c31 * 256 + ((ks * 32 + h2 * 16) ^ ((c31 & 7) << 4));
            half8 bh = *(const half8*)(bb + bo);
            half8 bl = *(const half8*)(bb + 8192 + bo);
            acc1 = __builtin_amdgcn_mfma_f32_32x32x16_f16(ahi[ks], bh, acc1, 0, 0, 0);
            acc2 = __builtin_amdgcn_mfma_f32_32x32x16_f16(alo[ks], bh, acc2, 0, 0, 0);
            if (ks & 1)
                acc2 = __builtin_amdgcn_mfma_f32_32x32x16_f16(ahi[ks], bl, acc2, 0, 0, 0);
            else
                acc1 = __builtin_amdgcn_mfma_f32_32x32x16_f16(ahi[ks], bl, acc1, 0, 0, 0);
        }
        __builtin_amdgcn_s_setprio(0);

        int kidx = half * 2048 + ct * 32 + c31;   // C/D: col = l&31
#pragma unroll
        for (int j = 0; j < 16; ++j) {
            float v = acc1[j] + acc2[j];
            if (v < minv[j]) { minv[j] = v; mini[j] = kidx; }
        }

        __builtin_amdgcn_s_barrier();   // all reads of tile p done -> safe to overwrite
    }

    // argmin reduce across the 32 col-lanes (low 5 lane bits)
#pragma unroll
    for (int off = 1; off < 32; off <<= 1) {
#pragma unroll
        for (int j = 0; j < 16; ++j) {
            float v2 = __shfl_xor(minv[j], off);
            int   i2 = __shfl_xor(mini[j], off);
            if (v2 < minv[j] || (v2 == minv[j] && i2 < mini[j])) { minv[j] = v2; mini[j] = i2; }
        }
    }
    // combine halves: key = (monotonic(score)<<32)|idx, atomicMin; second arriver finishes.
    if (c31 == 0) {
#pragma unroll
        for (int j = 0; j < 16; ++j) {
            // C/D: row = (reg&3) + 8*(reg>>2) + 4*(l>>5)
            int row = row0 + w * 32 + (j & 3) + 8 * (j >> 2) + 4 * h2;
            unsigned int u = __float_as_uint(minv[j]);
            u = (u & 0x80000000u) ? ~u : (u | 0x80000000u);
            unsigned long long key = ((unsigned long long)u << 32) | (unsigned int)mini[j];
            unsigned long long old = atomicMin(&rowpack[row], key);
            if (old != ~0ULL) {
                unsigned long long fin = old < key ? old : key;
                int kf = (int)(fin & 0xFFFFFFFFu);
                out[OFF_IDX + row] = (float)kf;
                sidx[row] = kf;
                atomicAdd(&counts[kf], 1u);
            }
        }
    }
}

// ---------------- scan: shfl-based prefix sum of counts; ncs, inv_sm ----------------
__global__ __launch_bounds__(256) void vq_scan_kernel(const unsigned int* __restrict__ counts,
                                                      const float* __restrict__ cs,
                                                      float* __restrict__ out,
                                                      int* __restrict__ offsets,
                                                      int* __restrict__ cursor,
                                                      float* __restrict__ inv_sm) {
    __shared__ int   wsum[4];
    __shared__ float wnsum[4];
    int tid = threadIdx.x, l = tid & 63, w = tid >> 6;

    unsigned int c[16];
    float vl[16];
    int   csum = 0;
    float nsum = 0.f;
#pragma unroll
    for (int j = 0; j < 16; ++j) {
        int i = tid * 16 + j;
        c[j] = counts[i];
        csum += (int)c[j];
        float v = fmaf(cs[i], DECAY_F, (float)c[j] * ONE_MINUS_DECAY);
        vl[j] = v;
        nsum += v;
        out[OFF_NCS + i] = v;
    }

    int inc = csum;
#pragma unroll
    for (int off = 1; off < 64; off <<= 1) {
        int t = __shfl_up(inc, off);
        if (l >= off) inc += t;
    }
    float nred = nsum;
#pragma unroll
    for (int off = 32; off >= 1; off >>= 1) nred += __shfl_xor(nred, off);

    if (l == 63) wsum[w] = inc;
    if (l == 0)  wnsum[w] = nred;
    __syncthreads();

    int wpre = 0;
    for (int i = 0; i < w; ++i) wpre += wsum[i];
    float ntot = wnsum[0] + wnsum[1] + wnsum[2] + wnsum[3];
    float num  = ntot + (float)KCODES * EPS_F;

    int off_ = wpre + inc - csum;
#pragma unroll
    for (int j = 0; j < 16; ++j) {
        int i = tid * 16 + j;
        offsets[i] = off_;
        cursor[i]  = off_;
        off_ += (int)c[j];
        inv_sm[i] = num / ((vl[j] + EPS_F) * ntot);
    }
}

// ---------------- sort: bucket rows by code; emit rowids + skey ----------------
__global__ __launch_bounds__(256) void vq_sort_kernel(const int* __restrict__ sidx,
                                                      int* __restrict__ cursor,
                                                      int* __restrict__ rowids,
                                                      int* __restrict__ skey) {
    int r = blockIdx.x * 256 + threadIdx.x;
    int k = sidx[r];
    int pos = atomicAdd(&cursor[k], 1);
    rowids[pos] = r;
    skey[pos]   = k;
}

// ---------------- segsum: position-parallel sorted segment sum (run-flush) ----------------
__global__ __launch_bounds__(256) void vq_segsum_kernel(const float* __restrict__ x,
                                                        const float* __restrict__ embed,
                                                        const int* __restrict__ rowids,
                                                        const int* __restrict__ skey,
                                                        const int* __restrict__ offsets,
                                                        const unsigned int* __restrict__ counts,
                                                        float* __restrict__ esum,
                                                        float* __restrict__ out) {
    __shared__ float buck[64][DIM];     // 32 KB
    __shared__ int   rid_s[64], rank_s[64], bcode_s[64];
    __shared__ int   nseg_s;
    __shared__ float lred[4];

    const int tid = threadIdx.x;
    const int w   = tid >> 6, l = tid & 63;
    const int p0  = blockIdx.x * 64;

    {
        float4* bz = (float4*)&buck[0][0];
#pragma unroll
        for (int j = 0; j < 8; ++j) bz[j * 256 + tid] = (float4){0.f, 0.f, 0.f, 0.f};
    }

    if (tid < 64) {
        int p = p0 + tid;
        int k = skey[p];
        rid_s[tid] = rowids[p];
        int f = (tid == 0) ? 1 : (k != skey[p - 1] ? 1 : 0);
        int inc = f;
#pragma unroll
        for (int off = 1; off < 64; off <<= 1) {
            int t = __shfl_up(inc, off);
            if (tid >= off) inc += t;
        }
        int rank = inc - 1;
        rank_s[tid] = rank;
        if (f) bcode_s[rank] = k;
        if (tid == 63) nseg_s = inc;
    }
    __syncthreads();

    float lsum = 0.f;
    {
        int prevb = rank_s[w * 16];
        float2 ev = *(const float2*)(embed + (size_t)bcode_s[prevb] * DIM + l * 2);
        float ra0 = 0.f, ra1 = 0.f;
#pragma unroll 4
        for (int i = 0; i < 16; ++i) {
            int pl = w * 16 + i;
            int r  = rid_s[pl];
            int b  = rank_s[pl];
            if (b != prevb) {
                atomicAdd(&buck[prevb][l * 2],     ra0);
                atomicAdd(&buck[prevb][l * 2 + 1], ra1);
                ra0 = 0.f; ra1 = 0.f;
                prevb = b;
                ev = *(const float2*)(embed + (size_t)bcode_s[b] * DIM + l * 2);
            }
            float2 xv = *(const float2*)(x + (size_t)r * DIM + l * 2);
            *(float2*)(out + (size_t)r * DIM + l * 2) = ev;     // quantize gather
            ra0 += xv.x; ra1 += xv.y;
            float d0 = ev.x - xv.x, d1 = ev.y - xv.y;
            lsum = fmaf(d0, d0, fmaf(d1, d1, lsum));
        }
        atomicAdd(&buck[prevb][l * 2],     ra0);
        atomicAdd(&buck[prevb][l * 2 + 1], ra1);
    }

#pragma unroll
    for (int s = 32; s >= 1; s >>= 1) lsum += __shfl_xor(lsum, s);
    if (l == 0) lred[w] = lsum;
    __syncthreads();

    int nseg = nseg_s;
    for (int b = w; b < nseg; b += 4) {
        int kb = bcode_s[b];
        int o  = offsets[kb];
        int c  = (int)counts[kb];
        float v0 = buck[b][l * 2], v1 = buck[b][l * 2 + 1];
        if (o >= p0 && o + c <= p0 + 64) {
            *(float2*)(esum + (size_t)kb * DIM + l * 2) = (float2){v0, v1};
        } else {
            atomicAdd(esum + (size_t)kb * DIM + l * 2,     v0);
            atomicAdd(esum + (size_t)kb * DIM + l * 2 + 1, v1);
        }
    }

    if (tid == 0) {
        float bl = (lred[0] + lred[1]) + (lred[2] + lred[3]);
        atomicAdd(out + OFF_LOSS, bl * (1.0f / ((float)NPTS * (float)DIM)));
    }
}

// ---------------- embed: new_embed = (eavg*0.99 + esum*0.01) * inv_sm ----------------
__global__ __launch_bounds__(256) void vq_embed_kernel(const float* __restrict__ eavg,
                                                       const float* __restrict__ esum,
                                                       const float* __restrict__ inv_sm,
                                                       float* __restrict__ out) {
    int i = blockIdx.x * 256 + threadIdx.x;
    int k = i >> 7;
    out[OFF_EMB + i] = fmaf(eavg[i], DECAY_F, esum[i] * ONE_MINUS_DECAY) * inv_sm[k];
}

extern "C" void kernel_launch(void* const* d_in, const int* in_sizes, int n_in,
                              void* d_out, int out_size, void* d_ws, size_t ws_size,
                              hipStream_t stream) {
    const float* x     = (const float*)d_in[0];
    const float* embed = (const float*)d_in[1];
    const float* cs    = (const float*)d_in[2];
    const float* eavg  = (const float*)d_in[3];
    float* out = (float*)d_out;

    // ws: rowpack[N] u64 | esq[K] | inv_sm[K] | counts[K] | offsets[K] | cursor[K] |
    //     rowids[N] | sidx[N] | skey[N] | esum[K*D] | Eimg 2MB   (~5.9 MB)
    unsigned long long* rowpack = (unsigned long long*)d_ws;
    float*         esq     = (float*)(rowpack + NPTS);
    float*         inv_sm  = esq + KCODES;
    unsigned int*  counts  = (unsigned int*)(inv_sm + KCODES);
    int*           offsets = (int*)(counts + KCODES);
    int*           cursor  = offsets + KCODES;
    int*           rowids  = cursor + KCODES;
    int*           sidx    = rowids + NPTS;
    int*           skey    = sidx + NPTS;
    float*         esum    = (float*)(skey + NPTS);
    unsigned char* Eimg    = (unsigned char*)(esum + KCODES * DIM);

    vq_prep_kernel<<<KCODES / 32, 256, 0, stream>>>(embed, esq, Eimg, rowpack, counts, esum, out);
    vq_main_kernel<<<NPTS / 128 * 2, 256, 0, stream>>>(x, esq, Eimg, rowpack, counts, sidx, out);
    vq_scan_kernel<<<1, 256, 0, stream>>>(counts, cs, out, offsets, cursor, inv_sm);
    vq_sort_kernel<<<NPTS / 256, 256, 0, stream>>>(sidx, cursor, rowids, skey);
    vq_segsum_kernel<<<NPTS / 64, 256, 0, stream>>>(x, embed, rowids, skey, offsets, counts, esum, out);
    vq_embed_kernel<<<(KCODES * DIM) / 256, 256, 0, stream>>>(eavg, esum, inv_sm, out);
}

// Round 12
// 222.533 us; speedup vs baseline: 1.3152x; 1.2218x over previous
//
#include <hip/hip_runtime.h>
#include <math.h>

#define NPTS   65536
#define DIM    128
#define KCODES 4096

constexpr float DECAY_F         = 0.99f;
constexpr float ONE_MINUS_DECAY = 0.01f;
constexpr float EPS_F           = 1e-5f;

// d_out layout (floats): quantize_st[N*D] | embed_ind[N] | loss[1] | new_embed[K*D] | new_cluster_size[K]
constexpr int OFF_IDX  = NPTS * DIM;
constexpr int OFF_LOSS = OFF_IDX + NPTS;
constexpr int OFF_EMB  = OFF_LOSS + 1;
constexpr int OFF_NCS  = OFF_EMB + KCODES * DIM;

typedef _Float16 half8 __attribute__((ext_vector_type(8)));
typedef _Float16 half4 __attribute__((ext_vector_type(4)));
typedef float    f32x4 __attribute__((ext_vector_type(4)));

// ---------------- prep: E image + esq + ALL buffer init (no memsets) ----------------
__global__ __launch_bounds__(256) void vq_prep_kernel(const float* __restrict__ embed,
                                                      float* __restrict__ esq,
                                                      unsigned char* __restrict__ Eimg,
                                                      unsigned long long* __restrict__ rowpack,
                                                      unsigned int* __restrict__ counts,
                                                      float* __restrict__ esum,
                                                      float* __restrict__ out) {
    __shared__ float sq[512];
    int b = blockIdx.x, t = threadIdx.x;

    rowpack[b * 512 + t]       = ~0ULL;
    rowpack[b * 512 + 256 + t] = ~0ULL;
    if (t < 32) counts[b * 32 + t] = 0u;
    if (b == 0 && t == 0) out[OFF_LOSS] = 0.f;

    {
        float4* ez = (float4*)esum;
#pragma unroll
        for (int j = 0; j < 4; ++j) ez[(size_t)b * 1024 + j * 256 + t] = (float4){0.f, 0.f, 0.f, 0.f};
    }

    unsigned char* img = Eimg + ((size_t)b << 14);
#pragma unroll
    for (int it = 0; it < 2; ++it) {
        int idx = t + it * 256;            // 0..511 : (r 0..31, c8 0..15)
        int r = idx >> 4, c8 = idx & 15;
        const float4* src = (const float4*)(embed + (size_t)(b * 32 + r) * DIM + c8 * 8);
        float4 v0 = src[0], v1 = src[1];
        float e[8] = {v0.x, v0.y, v0.z, v0.w, v1.x, v1.y, v1.z, v1.w};
        half8 h8, l8;
        float ss = 0.f;
#pragma unroll
        for (int j = 0; j < 8; ++j) {
            _Float16 h = (_Float16)e[j];
            h8[j] = h;
            l8[j] = (_Float16)(e[j] - (float)h);
            ss = fmaf(e[j], e[j], ss);
        }
        int bo = r * 256 + ((c8 * 16) ^ ((r & 7) << 4));
        *(half8*)(img + bo)        = h8;
        *(half8*)(img + 8192 + bo) = l8;
        sq[idx] = ss;
    }
    __syncthreads();
    if (t < 32) {
        float s = 0.f;
#pragma unroll
        for (int c = 0; c < 16; ++c) s += sq[t * 16 + c];
        esq[b * 32 + t] = s;
    }
}

// ---------------- main: R9 skeleton + min-update deferred into the stage-wait window ----------------
__global__ __launch_bounds__(256, 4)
void vq_main_kernel(const float* __restrict__ x, const float* __restrict__ esq,
                    const unsigned char* __restrict__ Eimg,
                    unsigned long long* __restrict__ rowpack,
                    unsigned int* __restrict__ counts,
                    int* __restrict__ sidx,
                    float* __restrict__ out) {
    __shared__ __align__(16) unsigned char lds[40960];   // 32KB E dbuf + 8KB esq

    const int tid  = threadIdx.x;
    const int l    = tid & 63;
    const int w    = tid >> 6;          // 0..3
    const int mblk = blockIdx.x >> 1;
    const int half = blockIdx.x & 1;
    const int row0 = mblk * 128;

    // esq for this half -> LDS
    {
        const float4* eq = (const float4*)(esq + half * 2048);
        float4* dst = (float4*)(lds + 32768);
        dst[tid]       = eq[tid];
        dst[tid + 256] = eq[tid + 256];
    }

    // ---- X prologue: two 64-row phases through LDS; A = -2x f16 hi/lo -> registers ----
    half8 ahi[2][4], alo[2][4];
#pragma unroll
    for (int ph = 0; ph < 2; ++ph) {
        if (ph) __syncthreads();
        const float4* xg = (const float4*)(x + (size_t)(row0 + ph * 64) * DIM);
#pragma unroll
        for (int it = 0; it < 8; ++it) {
            int i4 = tid + it * 256;           // 0..2047 : 64 rows x 32 f4
            int r = i4 >> 5, c4 = i4 & 31;
            float4 v = xg[i4];
            float m0 = -2.f * v.x, m1 = -2.f * v.y, m2 = -2.f * v.z, m3 = -2.f * v.w;
            half4 h, lo;
            h[0] = (_Float16)m0; h[1] = (_Float16)m1; h[2] = (_Float16)m2; h[3] = (_Float16)m3;
            lo[0] = (_Float16)(m0 - (float)h[0]); lo[1] = (_Float16)(m1 - (float)h[1]);
            lo[2] = (_Float16)(m2 - (float)h[2]); lo[3] = (_Float16)(m3 - (float)h[3]);
            int bo = r * 256 + ((c4 * 8) ^ ((r & 7) << 4));
            *(half4*)(lds + bo)         = h;
            *(half4*)(lds + 16384 + bo) = lo;
        }
        __syncthreads();
        if ((w >> 1) == ph) {
#pragma unroll
            for (int rf = 0; rf < 2; ++rf)
#pragma unroll
                for (int ks = 0; ks < 4; ++ks) {
                    int rloc = (w & 1) * 32 + rf * 16 + (l & 15);
                    int bo = rloc * 256 + ((ks * 64 + (l >> 4) * 16) ^ ((rloc & 7) << 4));
                    ahi[rf][ks] = *(const half8*)(lds + bo);
                    alo[rf][ks] = *(const half8*)(lds + 16384 + bo);
                }
        }
    }
    __syncthreads();   // lds[0..32768] becomes E double-buffer (16KB each)

#define STAGE(P, CT)                                                                     \
    {                                                                                    \
        const unsigned char* gsrc = Eimg + ((size_t)(half * 64 + (CT)) << 14);           \
        _Pragma("unroll")                                                                \
        for (int t = 0; t < 4; ++t) {                                                    \
            __builtin_amdgcn_global_load_lds(                                            \
                (const __attribute__((address_space(1))) unsigned int*)(gsrc + t * 4096 + w * 1024 + l * 16), \
                (__attribute__((address_space(3))) unsigned int*)(lds + (P) * 16384 + t * 4096 + w * 1024),   \
                16, 0, 0);                                                               \
        }                                                                                \
    }

// deferred min-update of acc for iteration CT (runs in the NEXT iteration's stage-wait slack)
#define MIN_UPDATE(CT)                                                                   \
    {                                                                                    \
        _Pragma("unroll")                                                                \
        for (int rf = 0; rf < 2; ++rf)                                                   \
            _Pragma("unroll")                                                            \
            for (int cf = 0; cf < 2; ++cf) {                                             \
                int kidx = half * 2048 + (CT) * 32 + cf * 16 + (l & 15);                 \
                _Pragma("unroll")                                                        \
                for (int r = 0; r < 4; ++r) {                                            \
                    float v = acc[rf][cf][r];                                            \
                    if (v < minv[rf][r]) { minv[rf][r] = v; mini[rf][r] = kidx; }        \
                }                                                                        \
            }                                                                            \
    }

    float minv[2][4];
    int   mini[2][4];
#pragma unroll
    for (int rf = 0; rf < 2; ++rf)
#pragma unroll
        for (int r = 0; r < 4; ++r) { minv[rf][r] = 3.4e38f; mini[rf][r] = 0; }

    const float* esql = (const float*)(lds + 32768);
    f32x4 acc[2][2];

    STAGE(0, 0);

    for (int ct = 0; ct < 64; ++ct) {
        const int p = ct & 1;
        // issue next tile, then retire the PREVIOUS iteration's min-update in the
        // wait window, then counted-vmcnt (T4) + barrier.
        if (ct < 63) {
            STAGE(p ^ 1, ct + 1);
            if (ct > 0) MIN_UPDATE(ct - 1);
            __builtin_amdgcn_sched_barrier(0);   // pin the update above the wait
            asm volatile("s_waitcnt vmcnt(4)" ::: "memory");
        } else {
            MIN_UPDATE(62);
            __builtin_amdgcn_sched_barrier(0);
            asm volatile("s_waitcnt vmcnt(0)" ::: "memory");
        }
        __builtin_amdgcn_s_barrier();   // all waves' tile-p loads landed

        const unsigned char* bb = lds + p * 16384;

        // esq folded into accumulator init
        float ecf[2];
        ecf[0] = esql[ct * 32 + (l & 15)];
        ecf[1] = esql[ct * 32 + 16 + (l & 15)];
#pragma unroll
        for (int rf = 0; rf < 2; ++rf)
#pragma unroll
            for (int cf = 0; cf < 2; ++cf) {
                float e = ecf[cf];
                acc[rf][cf] = (f32x4){e, e, e, e};
            }

        __builtin_amdgcn_s_setprio(1);
#pragma unroll
        for (int ks = 0; ks < 4; ++ks) {
#pragma unroll
            for (int cf = 0; cf < 2; ++cf) {
                int rowb = cf * 16 + (l & 15);
                int bo = rowb * 256 + ((ks * 64 + (l >> 4) * 16) ^ ((rowb & 7) << 4));
                half8 bh = *(const half8*)(bb + bo);
                half8 bl = *(const half8*)(bb + 8192 + bo);
                acc[0][cf] = __builtin_amdgcn_mfma_f32_16x16x32_f16(ahi[0][ks], bh, acc[0][cf], 0, 0, 0);
                acc[1][cf] = __builtin_amdgcn_mfma_f32_16x16x32_f16(ahi[1][ks], bh, acc[1][cf], 0, 0, 0);
                acc[0][cf] = __builtin_amdgcn_mfma_f32_16x16x32_f16(alo[0][ks], bh, acc[0][cf], 0, 0, 0);
                acc[1][cf] = __builtin_amdgcn_mfma_f32_16x16x32_f16(alo[1][ks], bh, acc[1][cf], 0, 0, 0);
                acc[0][cf] = __builtin_amdgcn_mfma_f32_16x16x32_f16(ahi[0][ks], bl, acc[0][cf], 0, 0, 0);
                acc[1][cf] = __builtin_amdgcn_mfma_f32_16x16x32_f16(ahi[1][ks], bl, acc[1][cf], 0, 0, 0);
            }
        }
        __builtin_amdgcn_s_setprio(0);

        __builtin_amdgcn_s_barrier();   // all reads of tile p done -> safe to overwrite
    }
    MIN_UPDATE(63);

    // argmin reduce across the 16 col-lanes (low 4 lane bits)
#pragma unroll
    for (int off = 1; off < 16; off <<= 1) {
#pragma unroll
        for (int rf = 0; rf < 2; ++rf)
#pragma unroll
            for (int r = 0; r < 4; ++r) {
                float v2 = __shfl_xor(minv[rf][r], off);
                int   i2 = __shfl_xor(mini[rf][r], off);
                if (v2 < minv[rf][r] || (v2 == minv[rf][r] && i2 < mini[rf][r])) {
                    minv[rf][r] = v2; mini[rf][r] = i2;
                }
            }
    }
    // combine halves: key = (monotonic(score)<<32)|idx, atomicMin; second arriver finishes.
    if ((l & 15) == 0) {
#pragma unroll
        for (int rf = 0; rf < 2; ++rf)
#pragma unroll
            for (int r = 0; r < 4; ++r) {
                int row = row0 + w * 32 + rf * 16 + (l >> 4) * 4 + r;   // C/D: row=(l>>4)*4+reg
                unsigned int u = __float_as_uint(minv[rf][r]);
                u = (u & 0x80000000u) ? ~u : (u | 0x80000000u);
                unsigned long long key = ((unsigned long long)u << 32) | (unsigned int)mini[rf][r];
                unsigned long long old = atomicMin(&rowpack[row], key);
                if (old != ~0ULL) {
                    unsigned long long fin = old < key ? old : key;
                    int kf = (int)(fin & 0xFFFFFFFFu);
                    out[OFF_IDX + row] = (float)kf;
                    sidx[row] = kf;
                    atomicAdd(&counts[kf], 1u);
                }
            }
    }
}

// ---------------- scan: shfl-based prefix sum of counts; ncs, inv_sm ----------------
__global__ __launch_bounds__(256) void vq_scan_kernel(const unsigned int* __restrict__ counts,
                                                      const float* __restrict__ cs,
                                                      float* __restrict__ out,
                                                      int* __restrict__ offsets,
                                                      int* __restrict__ cursor,
                                                      float* __restrict__ inv_sm) {
    __shared__ int   wsum[4];
    __shared__ float wnsum[4];
    int tid = threadIdx.x, l = tid & 63, w = tid >> 6;

    unsigned int c[16];
    float vl[16];
    int   csum = 0;
    float nsum = 0.f;
#pragma unroll
    for (int j = 0; j < 16; ++j) {
        int i = tid * 16 + j;
        c[j] = counts[i];
        csum += (int)c[j];
        float v = fmaf(cs[i], DECAY_F, (float)c[j] * ONE_MINUS_DECAY);
        vl[j] = v;
        nsum += v;
        out[OFF_NCS + i] = v;
    }

    int inc = csum;
#pragma unroll
    for (int off = 1; off < 64; off <<= 1) {
        int t = __shfl_up(inc, off);
        if (l >= off) inc += t;
    }
    float nred = nsum;
#pragma unroll
    for (int off = 32; off >= 1; off >>= 1) nred += __shfl_xor(nred, off);

    if (l == 63) wsum[w] = inc;
    if (l == 0)  wnsum[w] = nred;
    __syncthreads();

    int wpre = 0;
    for (int i = 0; i < w; ++i) wpre += wsum[i];
    float ntot = wnsum[0] + wnsum[1] + wnsum[2] + wnsum[3];
    float num  = ntot + (float)KCODES * EPS_F;

    int off_ = wpre + inc - csum;
#pragma unroll
    for (int j = 0; j < 16; ++j) {
        int i = tid * 16 + j;
        offsets[i] = off_;
        cursor[i]  = off_;
        off_ += (int)c[j];
        inv_sm[i] = num / ((vl[j] + EPS_F) * ntot);
    }
}

// ---------------- sort: bucket rows by code; emit rowids + skey ----------------
__global__ __launch_bounds__(256) void vq_sort_kernel(const int* __restrict__ sidx,
                                                      int* __restrict__ cursor,
                                                      int* __restrict__ rowids,
                                                      int* __restrict__ skey) {
    int r = blockIdx.x * 256 + threadIdx.x;
    int k = sidx[r];
    int pos = atomicAdd(&cursor[k], 1);
    rowids[pos] = r;
    skey[pos]   = k;
}

// ---------------- segsum: position-parallel sorted segment sum (run-flush) ----------------
__global__ __launch_bounds__(256) void vq_segsum_kernel(const float* __restrict__ x,
                                                        const float* __restrict__ embed,
                                                        const int* __restrict__ rowids,
                                                        const int* __restrict__ skey,
                                                        const int* __restrict__ offsets,
                                                        const unsigned int* __restrict__ counts,
                                                        float* __restrict__ esum,
                                                        float* __restrict__ out) {
    __shared__ float buck[64][DIM];     // 32 KB
    __shared__ int   rid_s[64], rank_s[64], bcode_s[64];
    __shared__ int   nseg_s;
    __shared__ float lred[4];

    const int tid = threadIdx.x;
    const int w   = tid >> 6, l = tid & 63;
    const int p0  = blockIdx.x * 64;

    {
        float4* bz = (float4*)&buck[0][0];
#pragma unroll
        for (int j = 0; j < 8; ++j) bz[j * 256 + tid] = (float4){0.f, 0.f, 0.f, 0.f};
    }

    if (tid < 64) {
        int p = p0 + tid;
        int k = skey[p];
        rid_s[tid] = rowids[p];
        int f = (tid == 0) ? 1 : (k != skey[p - 1] ? 1 : 0);
        int inc = f;
#pragma unroll
        for (int off = 1; off < 64; off <<= 1) {
            int t = __shfl_up(inc, off);
            if (tid >= off) inc += t;
        }
        int rank = inc - 1;
        rank_s[tid] = rank;
        if (f) bcode_s[rank] = k;
        if (tid == 63) nseg_s = inc;
    }
    __syncthreads();

    float lsum = 0.f;
    {
        int prevb = rank_s[w * 16];
        float2 ev = *(const float2*)(embed + (size_t)bcode_s[prevb] * DIM + l * 2);
        float ra0 = 0.f, ra1 = 0.f;
#pragma unroll 4
        for (int i = 0; i < 16; ++i) {
            int pl = w * 16 + i;
            int r  = rid_s[pl];
            int b  = rank_s[pl];
            if (b != prevb) {
                atomicAdd(&buck[prevb][l * 2],     ra0);
                atomicAdd(&buck[prevb][l * 2 + 1], ra1);
                ra0 = 0.f; ra1 = 0.f;
                prevb = b;
                ev = *(const float2*)(embed + (size_t)bcode_s[b] * DIM + l * 2);
            }
            float2 xv = *(const float2*)(x + (size_t)r * DIM + l * 2);
            *(float2*)(out + (size_t)r * DIM + l * 2) = ev;     // quantize gather
            ra0 += xv.x; ra1 += xv.y;
            float d0 = ev.x - xv.x, d1 = ev.y - xv.y;
            lsum = fmaf(d0, d0, fmaf(d1, d1, lsum));
        }
        atomicAdd(&buck[prevb][l * 2],     ra0);
        atomicAdd(&buck[prevb][l * 2 + 1], ra1);
    }

#pragma unroll
    for (int s = 32; s >= 1; s >>= 1) lsum += __shfl_xor(lsum, s);
    if (l == 0) lred[w] = lsum;
    __syncthreads();

    int nseg = nseg_s;
    for (int b = w; b < nseg; b += 4) {
        int kb = bcode_s[b];
        int o  = offsets[kb];
        int c  = (int)counts[kb];
        float v0 = buck[b][l * 2], v1 = buck[b][l * 2 + 1];
        if (o >= p0 && o + c <= p0 + 64) {
            *(float2*)(esum + (size_t)kb * DIM + l * 2) = (float2){v0, v1};
        } else {
            atomicAdd(esum + (size_t)kb * DIM + l * 2,     v0);
            atomicAdd(esum + (size_t)kb * DIM + l * 2 + 1, v1);
        }
    }

    if (tid == 0) {
        float bl = (lred[0] + lred[1]) + (lred[2] + lred[3]);
        atomicAdd(out + OFF_LOSS, bl * (1.0f / ((float)NPTS * (float)DIM)));
    }
}

// ---------------- embed: new_embed = (eavg*0.99 + esum*0.01) * inv_sm ----------------
__global__ __launch_bounds__(256) void vq_embed_kernel(const float* __restrict__ eavg,
                                                       const float* __restrict__ esum,
                                                       const float* __restrict__ inv_sm,
                                                       float* __restrict__ out) {
    int i = blockIdx.x * 256 + threadIdx.x;
    int k = i >> 7;
    out[OFF_EMB + i] = fmaf(eavg[i], DECAY_F, esum[i] * ONE_MINUS_DECAY) * inv_sm[k];
}

extern "C" void kernel_launch(void* const* d_in, const int* in_sizes, int n_in,
                              void* d_out, int out_size, void* d_ws, size_t ws_size,
                              hipStream_t stream) {
    const float* x     = (const float*)d_in[0];
    const float* embed = (const float*)d_in[1];
    const float* cs    = (const float*)d_in[2];
    const float* eavg  = (const float*)d_in[3];
    float* out = (float*)d_out;

    // ws: rowpack[N] u64 | esq[K] | inv_sm[K] | counts[K] | offsets[K] | cursor[K] |
    //     rowids[N] | sidx[N] | skey[N] | esum[K*D] | Eimg 2MB   (~5.9 MB)
    unsigned long long* rowpack = (unsigned long long*)d_ws;
    float*         esq     = (float*)(rowpack + NPTS);
    float*         inv_sm  = esq + KCODES;
    unsigned int*  counts  = (unsigned int*)(inv_sm + KCODES);
    int*           offsets = (int*)(counts + KCODES);
    int*           cursor  = offsets + KCODES;
    int*           rowids  = cursor + KCODES;
    int*           sidx    = rowids + NPTS;
    int*           skey    = sidx + NPTS;
    float*         esum    = (float*)(skey + NPTS);
    unsigned char* Eimg    = (unsigned char*)(esum + KCODES * DIM);

    vq_prep_kernel<<<KCODES / 32, 256, 0, stream>>>(embed, esq, Eimg, rowpack, counts, esum, out);
    vq_main_kernel<<<NPTS / 128 * 2, 256, 0, stream>>>(x, esq, Eimg, rowpack, counts, sidx, out);
    vq_scan_kernel<<<1, 256, 0, stream>>>(counts, cs, out, offsets, cursor, inv_sm);
    vq_sort_kernel<<<NPTS / 256, 256, 0, stream>>>(sidx, cursor, rowids, skey);
    vq_segsum_kernel<<<NPTS / 64, 256, 0, stream>>>(x, embed, rowids, skey, offsets, counts, esum, out);
    vq_embed_kernel<<<(KCODES * DIM) / 256, 256, 0, stream>>>(eavg, esum, inv_sm, out);
}